// Round 1
// 458.953 us; speedup vs baseline: 1.1414x; 1.1414x over previous
//
#include <hip/hip_runtime.h>
#include <hip/hip_bf16.h>
#include <math.h>

#define M_ROWS 100000
#define NGROUPS 3125          // 100000 / 32 exactly
#define NTILES_TOTAL 391      // ceil(100000/256); tile 390 has rows 99840..99999 (5 full 32-row groups)
#define TILES_PER_XCD 49      // 8*49 = 392 >= 391
#define ROWS_PER_XCD 12500    // legacy path
#define NTILES 49             // legacy path
#define NCHUNK 49152          // weight: 49152 uint4 total == 49152 shorts per g-slice (96 KB)

typedef __attribute__((ext_vector_type(8)))  short  short8;
typedef __attribute__((ext_vector_type(16))) float  float16v;

__device__ __forceinline__ unsigned short bf16_rne(float f) {
    unsigned u = __builtin_bit_cast(unsigned, f);
    u += 0x7FFFu + ((u >> 16) & 1u);
    return (unsigned short)(u >> 16);
}

__device__ __forceinline__ float sigmoid_fast(float x) {
    return 1.0f / (1.0f + __expf(-x));
}
__device__ __forceinline__ float tanh_fast(float x) {
    return 1.0f - 2.0f / (__expf(2.0f * x) + 1.0f);   // correct limits at +/-inf
}

__device__ __forceinline__ unsigned pack2_rn(float lo, float hi) {
    __hip_bfloat162 t = __float22bfloat162_rn(float2{lo, hi});
    unsigned u;
    __builtin_memcpy(&u, &t, 4);
    return u;
}

// pack 8 f32 -> short8 bf16 (RNE)
__device__ __forceinline__ short8 pack_bf16x8(float4 a, float4 b) {
    union { short8 s; unsigned u[4]; } r;
    r.u[0] = pack2_rn(a.x, a.y);
    r.u[1] = pack2_rn(a.z, a.w);
    r.u[2] = pack2_rn(b.x, b.y);
    r.u[3] = pack2_rn(b.z, b.w);
    return r.s;
}

// ---------------------------------------------------------------------------
// prep (fused):
//  blocks [0, pack_blocks): pack X,H f32 -> bf16 A-fragment chunks.
//    unit u = gr*16+kc (u < 50000), lane = thread&63.
//    lane reads 8 f32 from row gr*32+(l&31), cols kc*16+(l>>5)*8  (2 lanes/64B line,
//    full line utilization) and writes 16B coalesced to
//    apack chunk (u*2+mat)*64+lane  (mat 0=X, 1=H).
//    => main kernel A-loads become lane-contiguous (1 KB per wave instruction).
//  next 192 blocks: weight swizzle f32 -> bf16 MFMA B-fragment chunk order.
//  next 391 blocks: row mask from `divided`.
//  last block: ordered-uint max init + done-counter reset.
// ---------------------------------------------------------------------------
__global__ void prep_kernel(const float* __restrict__ X,
                            const float* __restrict__ H,
                            const float* __restrict__ wih,
                            const float* __restrict__ whh,
                            const int* __restrict__ divided,
                            unsigned short* __restrict__ wswz,
                            unsigned short* __restrict__ apack,
                            unsigned int* __restrict__ maxacc,
                            int* __restrict__ maskbuf,
                            unsigned int* __restrict__ donecnt,
                            int pack_blocks)
{
    const int b   = blockIdx.x;
    const int tid = threadIdx.x;

    if (b < pack_blocks) {
        int gt   = b * 256 + tid;          // < 3,200,000 exactly
        int lane = gt & 63;
        int u    = gt >> 6;                // gr*16 + kc, < 50000
        int gr   = u >> 4;
        int kc   = u & 15;
        int row  = gr * 32 + (lane & 31);  // < 100000 exactly
        int col  = kc * 16 + (lane >> 5) * 8;
        const float* xs = X + (size_t)row * 256 + col;
        const float* hs = H + (size_t)row * 256 + col;
        float4 a = reinterpret_cast<const float4*>(xs)[0];
        float4 c = reinterpret_cast<const float4*>(xs)[1];
        reinterpret_cast<short8*>(apack)[(size_t)(u * 2) * 64 + lane] = pack_bf16x8(a, c);
        float4 d = reinterpret_cast<const float4*>(hs)[0];
        float4 e = reinterpret_cast<const float4*>(hs)[1];
        reinterpret_cast<short8*>(apack)[(size_t)(u * 2 + 1) * 64 + lane] = pack_bf16x8(d, e);
        return;
    }

    int bb = b - pack_blocks;
    if (bb < 192) {
        int idx  = bb * 256 + tid;        // < 49152 exactly
        int lane = idx & 63;
        int t    = idx >> 6;              // 0..767
        int s    = t % 6;
        int t2   = t / 6;                 // 0..127
        int kc   = t2 & 15;
        int g    = t2 >> 4;               // 0..7
        int row  = (s % 3) * 256 + g * 32 + (lane & 31);
        int col  = kc * 16 + (lane >> 5) * 8;
        const float* src = (s < 3 ? wih : whh) + row * 256 + col;
        float4 a = reinterpret_cast<const float4*>(src)[0];
        float4 c = reinterpret_cast<const float4*>(src)[1];
        uint4 p;
        p.x = (unsigned)bf16_rne(a.x) | ((unsigned)bf16_rne(a.y) << 16);
        p.y = (unsigned)bf16_rne(a.z) | ((unsigned)bf16_rne(a.w) << 16);
        p.z = (unsigned)bf16_rne(c.x) | ((unsigned)bf16_rne(c.y) << 16);
        p.w = (unsigned)bf16_rne(c.z) | ((unsigned)bf16_rne(c.w) << 16);
        reinterpret_cast<uint4*>(wswz)[idx] = p;
    } else if (bb < 192 + 391) {
        int m = (bb - 192) * 256 + tid;
        if (m < M_ROWS)
            maskbuf[m] = (divided[3 * m] > 0) | (divided[3 * m + 1] > 0) | (divided[3 * m + 2] > 0);
    } else {
        maxacc[tid] = 0u;                 // below ordered-map(-inf)
        if (tid == 0) *donecnt = 0u;
    }
}

// ---------------------------------------------------------------------------
// main (packed A): persistent blocks, LDS-resident weight slice (96 KB),
// stream row tiles. grid = 256 = (xcd: blockIdx&7) x (g: slot&7) x (sub: slot>>3).
// Tile-aligned partition: xcd owns tiles [xcd*49, min(xcd*49+49, 391));
// all active 32-row groups are full (100000 % 32 == 0), so the hot loop and
// epilogue have NO per-row bounds checks.
// Hot loop per kc: 2 coalesced global bf16x8 chunk loads (4-deep prefetch)
// + 6 contiguous ds_read_b128 + 6 MFMA. No barriers after weight stage.
// Finalize fused into the last block to finish (atomic done-counter).
// ---------------------------------------------------------------------------
__global__ __launch_bounds__(512, 2) void gru_main_packed(
    const unsigned short* __restrict__ Apack,
    const float* __restrict__ H,                 // exact f32 h for epilogue
    const unsigned short* __restrict__ Wswz,
    const float* __restrict__ bih,
    const float* __restrict__ bhh,
    const int* __restrict__ maskbuf,
    const float* __restrict__ interval,
    const float* __restrict__ time_w,
    const float* __restrict__ time_b,
    float* __restrict__ hnew,                    // d_out + 256
    unsigned int* __restrict__ maxacc,
    unsigned int* __restrict__ donecnt,
    float* __restrict__ out)
{
    __shared__ unsigned short Wlds[49152];       // 96 KB (one g-slice)
    __shared__ int islast;

    const int tid  = threadIdx.x;
    const int lane = tid & 63;
    const int wave = tid >> 6;                   // 0..7
    const int l32  = lane & 31;
    const int hi   = lane >> 5;

    const int b    = blockIdx.x;
    const int xcd  = b & 7;
    const int slot = b >> 3;
    const int g    = slot & 7;                   // column group (32 cols)
    const int sub  = slot >> 3;                  // 0..3 tile interleave

    const int tbeg = xcd * TILES_PER_XCD + sub;
    const int tend = min(xcd * TILES_PER_XCD + TILES_PER_XCD, NTILES_TOTAL);

    // ---- one-time weight stage: contiguous 96 KB slice -> LDS ----
    {
        const uint4* ws = reinterpret_cast<const uint4*>(Wswz) + (size_t)g * 6144;
        uint4* wd = reinterpret_cast<uint4*>(Wlds);
        #pragma unroll
        for (int i = 0; i < 12; ++i) wd[i * 512 + tid] = ws[i * 512 + tid];
    }
    __syncthreads();

    const short8* wbase = reinterpret_cast<const short8*>(Wlds);
    const short8* A8b   = reinterpret_cast<const short8*>(Apack);
    const int jj = g * 32 + l32;
    const float bir = bih[jj], biz = bih[256 + jj], bin_ = bih[512 + jj];
    const float bhr = bhh[jj], bhz = bhh[256 + jj], bhn  = bhh[512 + jj];

    float colmax = -__builtin_inff();

    for (int t = tbeg; t < tend; t += 4) {
        const int wrow0 = t * 256 + wave * 32;   // always a multiple of 32
        if (wrow0 >= M_ROWS) continue;           // only tile 390, waves 5..7
        const int gr0 = wrow0 >> 5;
        // chunk(gr0, kc, mat) at short8 index gr0*2048 + kc*128 + mat*64 + lane
        const short8* A8 = A8b + (size_t)gr0 * 2048 + lane;

        float16v acc[6];
        #pragma unroll
        for (int s = 0; s < 6; ++s)
            #pragma unroll
            for (int q = 0; q < 16; ++q) acc[s][q] = 0.0f;

        // 4-deep A prefetch ring (coalesced 16B/lane chunk loads)
        short8 bx[4], bh[4];
        #pragma unroll
        for (int p = 0; p < 4; ++p) {
            bx[p] = A8[p * 128];
            bh[p] = A8[p * 128 + 64];
        }

        #pragma unroll
        for (int kc = 0; kc < 16; ++kc) {
            const int cur = kc & 3;              // static after unroll
            const short8 ax = bx[cur];
            const short8 ah = bh[cur];
            if (kc < 12) {                       // refill slot 4 ahead
                bx[cur] = A8[(kc + 4) * 128];
                bh[cur] = A8[(kc + 4) * 128 + 64];
            }
            const short8* wk = wbase + kc * 384 + lane;   // contiguous 1KB/wave reads
            acc[0] = __builtin_amdgcn_mfma_f32_32x32x16_bf16(ax, wk[0],   acc[0], 0, 0, 0);
            acc[1] = __builtin_amdgcn_mfma_f32_32x32x16_bf16(ax, wk[64],  acc[1], 0, 0, 0);
            acc[2] = __builtin_amdgcn_mfma_f32_32x32x16_bf16(ax, wk[128], acc[2], 0, 0, 0);
            acc[3] = __builtin_amdgcn_mfma_f32_32x32x16_bf16(ah, wk[192], acc[3], 0, 0, 0);
            acc[4] = __builtin_amdgcn_mfma_f32_32x32x16_bf16(ah, wk[256], acc[4], 0, 0, 0);
            acc[5] = __builtin_amdgcn_mfma_f32_32x32x16_bf16(ah, wk[320], acc[5], 0, 0, 0);
        }

        // ---- fused GRU epilogue: C/D map col=lane&31(=jj), row=(reg&3)+8*(reg>>2)+4*hi ----
        #pragma unroll
        for (int reg = 0; reg < 16; ++reg) {
            const int rl = (reg & 3) + 8 * (reg >> 2) + 4 * hi;
            const int m  = wrow0 + rl;           // always in range
            float gir = acc[0][reg] + bir;
            float giz = acc[1][reg] + biz;
            float gin = acc[2][reg] + bin_;
            float ghr = acc[3][reg] + bhr;
            float ghz = acc[4][reg] + bhz;
            float ghn = acc[5][reg] + bhn;
            float r = sigmoid_fast(gir + ghr);
            float z = sigmoid_fast(giz + ghz);
            float n = tanh_fast(gin + r * ghn);
            float hp = H[(size_t)m * 256 + jj];  // exact f32 h (L2/L3-hot)
            float hv = (1.0f - z) * n + z * hp;
            int mk = maskbuf[m];
            __builtin_nontemporal_store(mk ? hv : 0.0f, &hnew[(size_t)m * 256 + jj]);
            if (mk) colmax = fmaxf(colmax, hv);
        }
    }

    // one atomic per column per block (lanes l and l+32 share jj)
    colmax = fmaxf(colmax, __shfl_xor(colmax, 32));
    if (hi == 0) {
        unsigned bb = __builtin_bit_cast(unsigned, colmax);
        unsigned u  = (bb & 0x80000000u) ? ~bb : (bb | 0x80000000u);
        atomicMax(&maxacc[jj], u);
    }

    // ---- fused finalize: last block to finish unmaps max + adds time features ----
    __syncthreads();
    if (tid == 0) {
        __threadfence();
        islast = (atomicAdd(donecnt, 1u) == 255u) ? 1 : 0;
    }
    __syncthreads();
    if (islast && tid < 256) {
        unsigned u  = atomicMax(&maxacc[tid], 0u);     // coherent device-scope read
        unsigned bb2 = (u & 0x80000000u) ? (u & 0x7FFFFFFFu) : ~u;
        float mx  = __builtin_bit_cast(float, bb2);
        float inv = 1.0f / logf(interval[0] + 2.718281828459045f);
        out[tid]  = mx + tanhf(inv * time_w[tid] + time_b[tid]);
    }
}

// ---------------------------------------------------------------------------
// legacy path (fallback when workspace is too small for the packed-A buffer):
// identical to the previous best kernel.
// ---------------------------------------------------------------------------
__global__ __launch_bounds__(512, 2) void gru_main_legacy(
    const float* __restrict__ X,
    const float* __restrict__ H,
    const unsigned short* __restrict__ Wswz,
    const float* __restrict__ bih,
    const float* __restrict__ bhh,
    const int* __restrict__ maskbuf,
    float* __restrict__ hnew,
    unsigned int* __restrict__ maxacc)
{
    __shared__ unsigned short Wlds[NCHUNK];

    const int tid  = threadIdx.x;
    const int lane = tid & 63;
    const int wave = tid >> 6;
    const int l32  = lane & 31;
    const int hi   = lane >> 5;

    const int b    = blockIdx.x;
    const int xcd  = b & 7;
    const int slot = b >> 3;
    const int g    = slot & 7;
    const int sub  = slot >> 3;
    const int base  = xcd * ROWS_PER_XCD;
    const int limit = base + ROWS_PER_XCD;

    {
        const uint4* ws = reinterpret_cast<const uint4*>(Wswz) + (size_t)g * 6144;
        uint4* wd = reinterpret_cast<uint4*>(Wlds);
        #pragma unroll
        for (int i = 0; i < 12; ++i) wd[i * 512 + tid] = ws[i * 512 + tid];
    }
    __syncthreads();

    const short8* wbase = reinterpret_cast<const short8*>(Wlds);
    const int jj = g * 32 + l32;
    const float bir = bih[jj], biz = bih[256 + jj], bin_ = bih[512 + jj];
    const float bhr = bhh[jj], bhz = bhh[256 + jj], bhn  = bhh[512 + jj];

    float colmax = -__builtin_inff();

    for (int t = sub; t < NTILES; t += 4) {
        const int wrow0 = base + t * 256 + wave * 32;
        if (wrow0 >= limit) continue;
        const int arow = min(wrow0 + l32, limit - 1);
        const float4* X4 = reinterpret_cast<const float4*>(X) + (size_t)arow * 64;
        const float4* H4 = reinterpret_cast<const float4*>(H) + (size_t)arow * 64;

        float16v acc[6];
        #pragma unroll
        for (int s = 0; s < 6; ++s)
            #pragma unroll
            for (int q = 0; q < 16; ++q) acc[s][q] = 0.0f;

        float4 xb[2][4], hb[2][4];
        #pragma unroll
        for (int c = 0; c < 2; ++c)
            #pragma unroll
            for (int f = 0; f < 2; ++f) {
                int fi = c * 4 + hi * 2 + f;
                xb[0][c * 2 + f] = X4[fi];
                hb[0][c * 2 + f] = H4[fi];
            }

        #pragma unroll
        for (int q = 0; q < 8; ++q) {
            const int cur = q & 1, nxt = cur ^ 1;
            if (q < 7) {
                #pragma unroll
                for (int c = 0; c < 2; ++c)
                    #pragma unroll
                    for (int f = 0; f < 2; ++f) {
                        int fi = (q * 2 + 2 + c) * 4 + hi * 2 + f;
                        xb[nxt][c * 2 + f] = X4[fi];
                        hb[nxt][c * 2 + f] = H4[fi];
                    }
            }
            short8 ax[2], ah[2];
            #pragma unroll
            for (int c = 0; c < 2; ++c) {
                ax[c] = pack_bf16x8(xb[cur][c * 2], xb[cur][c * 2 + 1]);
                ah[c] = pack_bf16x8(hb[cur][c * 2], hb[cur][c * 2 + 1]);
            }
            #pragma unroll
            for (int c = 0; c < 2; ++c) {
                const int kc = q * 2 + c;
                const short8* wk = wbase + (kc * 6) * 64 + lane;
                acc[0] = __builtin_amdgcn_mfma_f32_32x32x16_bf16(ax[c], wk[0],   acc[0], 0, 0, 0);
                acc[1] = __builtin_amdgcn_mfma_f32_32x32x16_bf16(ax[c], wk[64],  acc[1], 0, 0, 0);
                acc[2] = __builtin_amdgcn_mfma_f32_32x32x16_bf16(ax[c], wk[128], acc[2], 0, 0, 0);
                acc[3] = __builtin_amdgcn_mfma_f32_32x32x16_bf16(ah[c], wk[192], acc[3], 0, 0, 0);
                acc[4] = __builtin_amdgcn_mfma_f32_32x32x16_bf16(ah[c], wk[256], acc[4], 0, 0, 0);
                acc[5] = __builtin_amdgcn_mfma_f32_32x32x16_bf16(ah[c], wk[320], acc[5], 0, 0, 0);
            }
        }

        #pragma unroll
        for (int reg = 0; reg < 16; ++reg) {
            int rl = (reg & 3) + 8 * (reg >> 2) + 4 * hi;
            int m  = wrow0 + rl;
            if (m < limit) {
                float gir = acc[0][reg] + bir;
                float giz = acc[1][reg] + biz;
                float gin = acc[2][reg] + bin_;
                float ghr = acc[3][reg] + bhr;
                float ghz = acc[4][reg] + bhz;
                float ghn = acc[5][reg] + bhn;
                float r = sigmoid_fast(gir + ghr);
                float z = sigmoid_fast(giz + ghz);
                float n = tanh_fast(gin + r * ghn);
                float hp = H[(size_t)m * 256 + jj];
                float hv = (1.0f - z) * n + z * hp;
                int mk = maskbuf[m];
                __builtin_nontemporal_store(mk ? hv : 0.0f, &hnew[(size_t)m * 256 + jj]);
                if (mk) colmax = fmaxf(colmax, hv);
            }
        }
    }

    colmax = fmaxf(colmax, __shfl_xor(colmax, 32));
    if (hi == 0) {
        unsigned bb = __builtin_bit_cast(unsigned, colmax);
        unsigned u  = (bb & 0x80000000u) ? ~bb : (bb | 0x80000000u);
        atomicMax(&maxacc[jj], u);
    }
}

__global__ void finalize_kernel(const unsigned int* __restrict__ maxacc,
                                const float* __restrict__ interval,
                                const float* __restrict__ time_w,
                                const float* __restrict__ time_b,
                                float* __restrict__ out)
{
    int j = threadIdx.x;
    unsigned u = maxacc[j];
    unsigned b = (u & 0x80000000u) ? (u & 0x7FFFFFFFu) : ~u;
    float mx = __builtin_bit_cast(float, b);
    float inv = 1.0f / logf(interval[0] + 2.718281828459045f);
    out[j] = mx + tanhf(inv * time_w[j] + time_b[j]);
}

extern "C" void kernel_launch(void* const* d_in, const int* in_sizes, int n_in,
                              void* d_out, int out_size, void* d_ws, size_t ws_size,
                              hipStream_t stream) {
    const float* interval = (const float*)d_in[0];
    const float* co       = (const float*)d_in[2];
    const int*   divided  = (const int*)d_in[3];
    const float* hidden   = (const float*)d_in[7];
    const float* wih      = (const float*)d_in[8];
    const float* whh      = (const float*)d_in[9];
    const float* bih      = (const float*)d_in[10];
    const float* bhh      = (const float*)d_in[11];
    const float* time_w   = (const float*)d_in[12];
    const float* time_b   = (const float*)d_in[13];

    float* out  = (float*)d_out;     // [256] output, then [100000*256] h_new
    float* hnew = out + 256;

    // ws layout:
    //   0        : swizzled bf16 weights (786432 B)
    //   786432   : maxacc (1024 B)
    //   787456   : mask (400000 B)
    //   1187456  : donecnt (64 B)
    //   2097152  : packed bf16 A  X|H fragment chunks (102,400,000 B)
    unsigned short* wswz    = (unsigned short*)d_ws;
    unsigned int*   maxacc  = (unsigned int*)((char*)d_ws + 786432);
    int*            maskbuf = (int*)((char*)d_ws + 787456);
    unsigned int*   donecnt = (unsigned int*)((char*)d_ws + 1187456);
    unsigned short* apack   = (unsigned short*)((char*)d_ws + 2097152);

    const size_t NEED = 2097152ull + 102400000ull;
    const bool packed = (ws_size >= NEED);
    const int pb = packed ? 12500 : 0;       // A-pack blocks (3.2M threads)

    prep_kernel<<<pb + 584, 256, 0, stream>>>(co, hidden, wih, whh, divided,
                                              wswz, apack, maxacc, maskbuf,
                                              donecnt, pb);

    if (packed) {
        gru_main_packed<<<256, 512, 0, stream>>>(apack, hidden, wswz, bih, bhh,
                                                 maskbuf, interval, time_w, time_b,
                                                 hnew, maxacc, donecnt, out);
    } else {
        gru_main_legacy<<<256, 512, 0, stream>>>(co, hidden, wswz,
                                                 bih, bhh, maskbuf, hnew, maxacc);
        finalize_kernel<<<1, 256, 0, stream>>>(maxacc, interval, time_w, time_b, out);
    }
}